// Round 6
// baseline (143.750 us; speedup 1.0000x reference)
//
#include <hip/hip_runtime.h>
#include <math.h>

// CoherentLoss: N=16384 trajectories, grid M ~= 2402 (x uniform, h=0.01).
// 2 dispatches:
//  K0 memset: pres bitmap + loss + barrier counters (8.2 KB)
//  K1 fused persistent kernel, grid 64 x CHUNKS = 512 blocks (2/CU, all
//     co-resident):
//     phase A (all blocks): LDS wpsi, local prep, y==0 builds pres + zeroes
//       binned, windowed |dxq|<=3.5 trapz via exp/rot recurrences, write
//       gt partials, threadfence + arrive. y!=0 blocks exit.
//     phase B (64 y==0 blocks, after 512-arrive barrier): popcount-rank scan,
//       chunk-sum partials (agent atomic loads: no kernel boundary -> must
//       bypass stale L1), vals recompute + rank scatter.
//     phase C (after 64-arrive barrier): loss reduce, last block sqrts.

#define PRES_WORDS 1024          // 65536 bins / 64 bits
#define PRES_BITS  65536
#define PRES_OFF   32768
#define CHUNKS     8
#define MCAP       2432          // >= M, LDS wpsi capacity
#define WINR       3.5f          // exp(-12.25) = 4.8e-6 -> truncation ~1e-4 in gt
#define NORM       0.8932438417380023f   // (2/pi)^0.25

#define AL(p) __hip_atomic_load((p), __ATOMIC_RELAXED, __HIP_MEMORY_SCOPE_AGENT)

__global__ void __launch_bounds__(256) fused_kernel(
    const float* __restrict__ f_re, const float* __restrict__ f_im,
    const float* __restrict__ q_re, const float* __restrict__ q_im,
    const float* __restrict__ p_re, const float* __restrict__ p_im,
    const float* __restrict__ x, const float* __restrict__ psi,
    unsigned long long* __restrict__ pres,
    float* __restrict__ bre, float* __restrict__ bim,
    float* __restrict__ gpre, float* __restrict__ gpim,
    int* __restrict__ arrive1, int* __restrict__ arrive2,
    float* __restrict__ loss, int* __restrict__ fin,
    float* __restrict__ out, int n, int M)
{
    __shared__ float swpsi[MCAP];            // 9.7 KB: trapz weight * psi * norm
    __shared__ int lbase[PRES_WORDS];        // 4 KB: rank base per 64-bin word
    __shared__ float lred[4];
    int tid = threadIdx.x;
    float x0 = x[0];
    float h  = x[1] - x0;                    // uniform step (~0.01)
    for (int m = tid; m < M; m += 256) {
        float w = (m == 0 || m == M - 1) ? 0.5f * h : h;
        swpsi[m] = w * psi[m] * NORM;
    }
    __syncthreads();
    int traw = blockIdx.x * 256 + tid;
    bool valid = traw < n;
    int t = valid ? traw : (n - 1);          // clamped: redundant work, no OOB
    int cyc = blockIdx.y;
    // ---- phase A: local prep (this thread's inputs only) ----
    float qi = q_im[t], pr = p_re[t];
    float qf = q_re[t] - 0.5f * p_im[t];     // g = 1, exact pow2 ops
    float pf = 2.0f * qi + pr;
    float qb = floorf((qf + 8.0f) / 0.125f);     // dq exact pow2
    float pb = floorf((pf + 10.0f) / 0.15625f);  // dp = 5/32 exact
    float qcn = (qb + 0.5f) * 0.125f - 8.0f;
    float pcn = (pb + 0.5f) * 0.15625f - 10.0f;
    int pidx = min(max((int)(qb * 128.0f + pb) + PRES_OFF, 0), PRES_BITS - 1);
    if (cyc == 0 && valid) {
        atomicOr(&pres[pidx >> 6], 1ull << (pidx & 63));
        bre[t] = 0.0f; bim[t] = 0.0f;
    }
    // windowed gt chunk: |x[m]-qc| <= WINR, x[m] = x0 + m*h
    float inv_h = 1.0f / h;
    int mlo = max(0, (int)((qcn - WINR - x0) * inv_h) - 1);
    int mhi = min(M, (int)((qcn + WINR - x0) * inv_h) + 2);
    int len = mhi - mlo; if (len < 0) len = 0;
    int ms = mlo + (len * cyc) / CHUNKS;
    int me = mlo + (len * (cyc + 1)) / CHUNKS;
    // recurrences: e_m = exp(-dx^2) via e*=u, u*=d; (sn,cs) rotation by pcn*h
    float dx0 = fmaf((float)ms, h, x0 - qcn);
    float e = __expf(-dx0 * dx0);
    float u = __expf(-h * (dx0 + dx0 + h));
    float d = __expf(-2.0f * h * h);
    float sn, cs, sd, cd;
    __sincosf(pcn * dx0, &sn, &cs);
    __sincosf(pcn * h, &sd, &cd);
    float sre = 0.0f, sim = 0.0f;
    for (int m = ms; m < me; m++) {
        float w = swpsi[m];                  // LDS gather: ~2 lanes/bank, free
        float tv = e * w;
        sre = fmaf(tv, cs, sre);             // integrand: w*e*(cos - i sin)
        sim = fmaf(-tv, sn, sim);
        e *= u; u *= d;
        float cn = fmaf(cs, cd, -sn * sd);
        sn = fmaf(sn, cd, cs * sd);
        cs = cn;
    }
    gpre[cyc * n + t] = sre;                 // exact write (clamped dups benign:
    gpim[cyc * n + t] = sim;                 //  same value, loss guarded by valid)
    // ---- barrier 1: arrive(512); only y==0 waits ----
    __threadfence();
    __syncthreads();
    if (tid == 0)
        __hip_atomic_fetch_add(arrive1, 1, __ATOMIC_ACQ_REL, __HIP_MEMORY_SCOPE_AGENT);
    if (cyc != 0) return;
    if (tid == 0) {
        int total = (int)(gridDim.x * gridDim.y);
        while (__hip_atomic_load(arrive1, __ATOMIC_ACQUIRE, __HIP_MEMORY_SCOPE_AGENT) < total)
            __builtin_amdgcn_s_sleep(2);
    }
    __syncthreads();
    // ---- phase B: rank scan (wave 0), chunk-sum, scatter ----
    if (tid < 64) {
        int cum[16];
        int tot = 0;
        for (int k = 0; k < 16; k++) {
            cum[k] = tot;
            tot += __popcll(AL(&pres[tid * 16 + k]));
        }
        int run = tot;
        for (int off = 1; off < 64; off <<= 1) {
            int up = __shfl_up(run, off);
            if (tid >= off) run += up;
        }
        int excl = run - tot;
        for (int k = 0; k < 16; k++) lbase[tid * 16 + k] = excl + cum[k];
    }
    __syncthreads();
    for (int c = 1; c < CHUNKS; c++) {       // other chunks: agent atomic loads
        sre += AL(&gpre[c * n + t]);
        sim += AL(&gpim[c * n + t]);
    }
    if (valid) {
        unsigned long long pw = AL(&pres[pidx >> 6]);
        int bit = pidx & 63;
        unsigned long long below = pw & ((bit == 0) ? 0ull : (~0ull >> (64 - bit)));
        int cid = lbase[pidx >> 6] + __popcll(below);
        float ea = NORM * expf(qi * qi);
        float s2, c2;
        __sincosf(pr * qi, &s2, &c2);
        float prr = fminf(fmaxf(ea * c2, -100.0f), 100.0f);
        float pri = fminf(fmaxf(ea * s2, -100.0f), 100.0f);
        float fr = f_re[t], fi = f_im[t];
        atomicAdd(&bre[cid], prr * fr - pri * fi);
        atomicAdd(&bim[cid], prr * fi + pri * fr);
    }
    // ---- barrier 2: arrive(64) among y==0 blocks ----
    __threadfence();
    __syncthreads();
    if (tid == 0) {
        __hip_atomic_fetch_add(arrive2, 1, __ATOMIC_ACQ_REL, __HIP_MEMORY_SCOPE_AGENT);
        while (__hip_atomic_load(arrive2, __ATOMIC_ACQUIRE, __HIP_MEMORY_SCOPE_AGENT)
               < (int)gridDim.x)
            __builtin_amdgcn_s_sleep(2);
    }
    __syncthreads();
    // ---- phase C: loss ----
    float v = 0.0f;
    if (valid) {
        float dre = AL(&bre[t]) - sre;
        float dim = AL(&bim[t]) - sim;
        v = dre * dre + dim * dim;
    }
#pragma unroll
    for (int off = 32; off > 0; off >>= 1) v += __shfl_down(v, off);
    int wv = tid >> 6, ln = tid & 63;
    if (ln == 0) lred[wv] = v;
    __syncthreads();
    if (tid == 0) {
        __hip_atomic_fetch_add(loss, lred[0] + lred[1] + lred[2] + lred[3],
                               __ATOMIC_ACQ_REL, __HIP_MEMORY_SCOPE_AGENT);
        int old = __hip_atomic_fetch_add(fin, 1, __ATOMIC_ACQ_REL,
                                         __HIP_MEMORY_SCOPE_AGENT);
        if (old == (int)gridDim.x - 1)       // last block: all adds visible
            out[0] = sqrtf(__hip_atomic_load(loss, __ATOMIC_ACQUIRE,
                                             __HIP_MEMORY_SCOPE_AGENT));
    }
}

extern "C" void kernel_launch(void* const* d_in, const int* in_sizes, int n_in,
                              void* d_out, int out_size, void* d_ws, size_t ws_size,
                              hipStream_t stream)
{
    const float* f_re = (const float*)d_in[0];
    const float* f_im = (const float*)d_in[1];
    const float* q_re = (const float*)d_in[2];
    const float* q_im = (const float*)d_in[3];
    const float* p_re = (const float*)d_in[4];
    const float* p_im = (const float*)d_in[5];
    const float* x    = (const float*)d_in[6];
    const float* psi  = (const float*)d_in[7];
    int n = in_sizes[0];   // 16384
    int M = in_sizes[6];   // ~2402 (<= MCAP)

    // workspace layout
    float* gpre = (float*)d_ws;                         // CHUNKS*n
    float* gpim = gpre + (size_t)CHUNKS * n;            // CHUNKS*n
    float* bre  = gpim + (size_t)CHUNKS * n;            // n
    float* bim  = bre + n;                              // n
    unsigned long long* pres = (unsigned long long*)(bim + n); // 1024 u64
    float* loss    = (float*)(pres + PRES_WORDS);
    int*   arrive1 = (int*)(loss + 1);
    int*   arrive2 = arrive1 + 1;
    int*   fin     = arrive2 + 1;

    // zero pres + loss + barrier counters (8.2 KB)
    hipMemsetAsync(pres, 0, PRES_WORDS * sizeof(unsigned long long) + 16, stream);

    int nb = (n + 255) / 256;   // 64 -> grid 64 x 8 = 512 blocks, 2/CU
    fused_kernel<<<dim3(nb, CHUNKS), 256, 0, stream>>>(
        f_re, f_im, q_re, q_im, p_re, p_im, x, psi,
        pres, bre, bim, gpre, gpim, arrive1, arrive2, loss, fin,
        (float*)d_out, n, M);
}

// Round 7
// 107.803 us; speedup vs baseline: 1.3335x; 1.3335x over previous
//
#include <hip/hip_runtime.h>
#include <math.h>

// CoherentLoss: N=16384 trajectories, grid M ~= 2402 (x uniform, h=0.01).
// Round-5 structure (fusion experiment in R6 regressed: per-block device-scope
// fences for cross-XCD coherence cost far more than kernel-boundary flushes).
// 3 dispatches:
//  K0 memset: pres bitmap + loss + done counters (8.2 KB)
//  K1 gt_kernel: per-thread prep (local qc/pc, y==0 builds pres + zeroes
//     binned), windowed |dxq|<=3.5 trapz via exp/rot recurrences (no trans in
//     loop), chunked over blockIdx.y, exact-write partials
//  K2 scatter_loss: chunk-sum partials in regs, recompute vals, popcount-rank
//     scatter, in-kernel grid barrier (64 blocks, co-resident), loss + sqrt.

#define PRES_WORDS 1024          // 65536 bins / 64 bits
#define PRES_BITS  65536
#define PRES_OFF   32768
#define CHUNKS     8
#define MCAP       2432          // >= M, LDS wpsi capacity
#define WINR       3.5f          // exp(-12.25)=4.8e-6 -> truncation negligible
#define NORM       0.8932438417380023f   // (2/pi)^0.25

__global__ void __launch_bounds__(256) gt_kernel(
    const float* __restrict__ q_re, const float* __restrict__ q_im,
    const float* __restrict__ p_re, const float* __restrict__ p_im,
    const float* __restrict__ x, const float* __restrict__ psi,
    unsigned long long* __restrict__ pres,
    float* __restrict__ bre, float* __restrict__ bim,
    float* __restrict__ gpre, float* __restrict__ gpim, int n, int M)
{
    __shared__ float swpsi[MCAP];            // 9.7 KB: trapz weight * psi * norm
    int tid = threadIdx.x;
    float x0 = x[0];
    float h  = x[1] - x0;                    // uniform step (~0.01)
    for (int m = tid; m < M; m += 256) {
        float w = (m == 0 || m == M - 1) ? 0.5f * h : h;
        swpsi[m] = w * psi[m] * NORM;
    }
    __syncthreads();
    int t = blockIdx.x * 256 + tid;
    if (t >= n) return;
    // local prep: bin centers from this thread's own inputs only
    float qi = q_im[t], pr = p_re[t];
    float qf = q_re[t] - 0.5f * p_im[t];     // g = 1, exact pow2 ops
    float pf = 2.0f * qi + pr;
    float qb = floorf((qf + 8.0f) / 0.125f);     // dq exact pow2
    float pb = floorf((pf + 10.0f) / 0.15625f);  // dp = 5/32 exact
    float qcn = (qb + 0.5f) * 0.125f - 8.0f;
    float pcn = (pb + 0.5f) * 0.15625f - 10.0f;
    if (blockIdx.y == 0) {                   // build presence bitmap + zero binned
        int b = (int)(qb * 128.0f + pb);
        int pidx = min(max(b + PRES_OFF, 0), PRES_BITS - 1);
        atomicOr(&pres[pidx >> 6], 1ull << (pidx & 63));
        bre[t] = 0.0f; bim[t] = 0.0f;
    }
    // window [mlo, mhi): |x[m] - qc| <= WINR; x[m] = x0 + m*h
    float inv_h = 1.0f / h;
    int mlo = max(0, (int)((qcn - WINR - x0) * inv_h) - 1);
    int mhi = min(M, (int)((qcn + WINR - x0) * inv_h) + 2);
    int len = mhi - mlo; if (len < 0) len = 0;
    int c = blockIdx.y;
    int ms = mlo + (len * c) / CHUNKS;
    int me = mlo + (len * (c + 1)) / CHUNKS;
    // recurrences: e_m = exp(-dx_m^2) via e*=u, u*=d; (sn,cs) rotation by pcn*h
    float dx0 = fmaf((float)ms, h, x0 - qcn);
    float e   = __expf(-dx0 * dx0);
    float u   = __expf(-h * (dx0 + dx0 + h));
    float d   = __expf(-2.0f * h * h);
    float sn, cs, sd, cd;
    __sincosf(pcn * dx0, &sn, &cs);
    __sincosf(pcn * h, &sd, &cd);
    float sre = 0.0f, sim = 0.0f;
    for (int m = ms; m < me; m++) {
        float w = swpsi[m];                  // LDS gather
        float tv = e * w;
        sre = fmaf(tv, cs, sre);             // integrand: w*e*(cos - i sin)
        sim = fmaf(-tv, sn, sim);
        e *= u; u *= d;                      // exp recurrence
        float cn = fmaf(cs, cd, -sn * sd);   // rotation recurrence
        sn = fmaf(sn, cd, cs * sd);
        cs = cn;
    }
    gpre[c * n + t] = sre;                   // exact write, no zero needed
    gpim[c * n + t] = sim;
}

// 64 blocks (co-resident on 256 CUs): chunk-sum gt in regs, recompute vals,
// rank-scatter into binned, grid barrier, per-slice loss, last block sqrts.
__global__ void __launch_bounds__(256) scatter_loss_kernel(
    const float* __restrict__ f_re, const float* __restrict__ f_im,
    const float* __restrict__ q_re, const float* __restrict__ q_im,
    const float* __restrict__ p_re, const float* __restrict__ p_im,
    const unsigned long long* __restrict__ pres,
    float* __restrict__ bre, float* __restrict__ bim,
    const float* __restrict__ gpre, const float* __restrict__ gpim,
    int* __restrict__ k3done, float* __restrict__ loss, int* __restrict__ fin,
    float* __restrict__ out, int n)
{
    __shared__ int lbase[PRES_WORDS];        // exclusive rank base per 64-bin word
    int tid = threadIdx.x;
    if (tid < 64) {
        int cum[16];
        int tot = 0;
        for (int k = 0; k < 16; k++) { cum[k] = tot; tot += __popcll(pres[tid * 16 + k]); }
        int run = tot;
        for (int off = 1; off < 64; off <<= 1) {
            int up = __shfl_up(run, off);
            if (tid >= off) run += up;
        }
        int excl = run - tot;
        for (int k = 0; k < 16; k++) lbase[tid * 16 + k] = excl + cum[k];
    }
    __syncthreads();
    int t = blockIdx.x * 256 + tid;
    // chunk-sum this thread's gt (kernel boundary made partials visible)
    float sre = 0.0f, sim = 0.0f;
    for (int c = 0; c < CHUNKS; c++) {
        sre += gpre[c * n + t];
        sim += gpim[c * n + t];
    }
    // recompute bin + vals, scatter into compact-rank binned accumulators
    float qi = q_im[t], pr = p_re[t];
    float qf = q_re[t] - 0.5f * p_im[t];
    float pf = 2.0f * qi + pr;
    float qb = floorf((qf + 8.0f) / 0.125f);
    float pb = floorf((pf + 10.0f) / 0.15625f);
    int b = (int)(qb * 128.0f + pb);
    int pidx = min(max(b + PRES_OFF, 0), PRES_BITS - 1);
    int w = pidx >> 6, bit = pidx & 63;
    unsigned long long below = pres[w] & ((bit == 0) ? 0ull : (~0ull >> (64 - bit)));
    int cid = lbase[w] + __popcll(below);
    float ea = NORM * expf(qi * qi);
    float s, c2;
    __sincosf(pr * qi, &s, &c2);
    float prr = fminf(fmaxf(ea * c2, -100.0f), 100.0f);
    float pri = fminf(fmaxf(ea * s, -100.0f), 100.0f);
    float fr = f_re[t], fi = f_im[t];
    atomicAdd(&bre[cid], prr * fr - pri * fi);
    atomicAdd(&bim[cid], prr * fi + pri * fr);
    // grid barrier: 64 blocks, all co-resident (grid << CU count)
    __threadfence();
    __syncthreads();
    if (tid == 0) {
        __hip_atomic_fetch_add(k3done, 1, __ATOMIC_ACQ_REL, __HIP_MEMORY_SCOPE_AGENT);
        while (__hip_atomic_load(k3done, __ATOMIC_ACQUIRE, __HIP_MEMORY_SCOPE_AGENT)
               < (int)gridDim.x)
            __builtin_amdgcn_s_sleep(4);
    }
    __syncthreads();
    // loss over this block's slice; atomic loads bypass stale L1
    float brt  = __hip_atomic_load(&bre[t], __ATOMIC_RELAXED, __HIP_MEMORY_SCOPE_AGENT);
    float bit2 = __hip_atomic_load(&bim[t], __ATOMIC_RELAXED, __HIP_MEMORY_SCOPE_AGENT);
    float dre = brt - sre;
    float dim = bit2 - sim;
    float v = dre * dre + dim * dim;
#pragma unroll
    for (int off = 32; off > 0; off >>= 1) v += __shfl_down(v, off);
    __shared__ float l[4];
    int wv = tid >> 6, ln = tid & 63;
    if (ln == 0) l[wv] = v;
    __syncthreads();
    if (tid == 0) {
        __hip_atomic_fetch_add(loss, l[0] + l[1] + l[2] + l[3],
                               __ATOMIC_ACQ_REL, __HIP_MEMORY_SCOPE_AGENT);
        int old = __hip_atomic_fetch_add(fin, 1, __ATOMIC_ACQ_REL,
                                         __HIP_MEMORY_SCOPE_AGENT);
        if (old == (int)gridDim.x - 1) {     // last block: all adds visible
            out[0] = sqrtf(__hip_atomic_load(loss, __ATOMIC_ACQUIRE,
                                             __HIP_MEMORY_SCOPE_AGENT));
        }
    }
}

extern "C" void kernel_launch(void* const* d_in, const int* in_sizes, int n_in,
                              void* d_out, int out_size, void* d_ws, size_t ws_size,
                              hipStream_t stream)
{
    const float* f_re = (const float*)d_in[0];
    const float* f_im = (const float*)d_in[1];
    const float* q_re = (const float*)d_in[2];
    const float* q_im = (const float*)d_in[3];
    const float* p_re = (const float*)d_in[4];
    const float* p_im = (const float*)d_in[5];
    const float* x    = (const float*)d_in[6];
    const float* psi  = (const float*)d_in[7];
    int n = in_sizes[0];   // 16384
    int M = in_sizes[6];   // ~2402 (<= MCAP)

    // workspace layout
    float* gpre = (float*)d_ws;                         // CHUNKS*n
    float* gpim = gpre + (size_t)CHUNKS * n;            // CHUNKS*n
    float* bre  = gpim + (size_t)CHUNKS * n;            // n
    float* bim  = bre + n;                              // n
    unsigned long long* pres = (unsigned long long*)(bim + n); // 1024 u64
    float* loss    = (float*)(pres + PRES_WORDS);
    int*   k3done  = (int*)(loss + 1);
    int*   fin     = k3done + 1;

    // zero pres + loss + counters (8.2 KB)
    hipMemsetAsync(pres, 0, PRES_WORDS * sizeof(unsigned long long) + 12, stream);

    int nb = (n + 255) / 256;   // 64 -> gt grid 64 x 8 = 512 blocks, 2/CU
    gt_kernel<<<dim3(nb, CHUNKS), 256, 0, stream>>>(q_re, q_im, p_re, p_im, x, psi,
                                                    pres, bre, bim, gpre, gpim, n, M);
    scatter_loss_kernel<<<nb, 256, 0, stream>>>(f_re, f_im, q_re, q_im, p_re, p_im,
                                                pres, bre, bim, gpre, gpim,
                                                k3done, loss, fin, (float*)d_out, n);
}